// Round 2
// baseline (1315.952 us; speedup 1.0000x reference)
//
#include <hip/hip_runtime.h>
#include <hip/hip_bf16.h>
#include <math.h>

typedef unsigned short u16;
typedef unsigned int u32;
typedef __attribute__((ext_vector_type(8))) short bf16x8;
typedef __attribute__((ext_vector_type(4))) float f32x4;
typedef __attribute__((ext_vector_type(4))) unsigned short u16x4;

#define MFMA16(a, b, c) __builtin_amdgcn_mfma_f32_16x16x32_bf16(a, b, c, 0, 0, 0)

// ---------- constants ----------
#define SB 2          // batch
#define SS 2048       // seq
#define SD 2048       // model dim
#define SH 16         // heads
#define SHD 128       // head dim
#define SHID 5888     // ffn hidden
#define ATT_SCALE 0.08838834764831845f
#define NEGINF_MASK -65504.0f

__device__ __forceinline__ u16 f2bf(float f) {
  union { float f; u32 u; } v; v.f = f;
  u32 r = v.u + 0x7FFFu + ((v.u >> 16) & 1u);
  return (u16)(r >> 16);
}
__device__ __forceinline__ float bf2f(u16 h) {
  union { u32 u; float f; } v; v.u = ((u32)h) << 16;
  return v.f;
}
__device__ __forceinline__ void async_copy16(const u16* g, u16* l) {
  __builtin_amdgcn_global_load_lds(
      (const __attribute__((address_space(1))) void*)g,
      (__attribute__((address_space(3))) void*)l, 16, 0, 0);
}

// ---------- fused fp32 -> bf16 convert over 6 weight tensors ----------
struct CvtArgs {
  const float* src[6];
  u16* dst[6];
  int end4[6];   // cumulative end in f32x4 units
};
__global__ __launch_bounds__(256) void cvt6_kernel(CvtArgs a, int total4) {
  const int stride = gridDim.x * 256;
  for (int i = blockIdx.x * 256 + threadIdx.x; i < total4; i += stride) {
    int seg = 0;
    #pragma unroll
    for (int s = 0; s < 5; ++s) seg += (i >= a.end4[s]) ? 1 : 0;
    const int base = (seg == 0) ? 0 : a.end4[seg - 1];
    const int j = i - base;
    f32x4 v = ((const f32x4*)a.src[seg])[j];
    u16x4 r;
    r.x = f2bf(v.x); r.y = f2bf(v.y); r.z = f2bf(v.z); r.w = f2bf(v.w);
    ((u16x4*)a.dst[seg])[j] = r;
  }
}

// ---------- fused 4x LayerNorm (x0,x1,x2 -> nq,nk,nv ; x3 -> fx), bf16 out ----------
__global__ __launch_bounds__(256) void ln4_kernel(
    const float* __restrict__ x0, const float* __restrict__ x1,
    const float* __restrict__ x2, const float* __restrict__ x3,
    const float* __restrict__ w0, const float* __restrict__ b0,
    const float* __restrict__ w1, const float* __restrict__ b1,
    const float* __restrict__ w2, const float* __restrict__ b2,
    const float* __restrict__ w3, const float* __restrict__ b3,
    u16* __restrict__ out) {
  const int row = blockIdx.x;          // 0..16383
  const int which = row >> 12;         // 4096 rows per input
  const int r = row & 4095;
  const float* x; const float* w; const float* b;
  if (which == 0)      { x = x0; w = w0; b = b0; }
  else if (which == 1) { x = x1; w = w1; b = b1; }
  else if (which == 2) { x = x2; w = w2; b = b2; }
  else                 { x = x3; w = w3; b = b3; }
  const float* xr = x + (size_t)r * SD;
  const int tid = threadIdx.x;
  f32x4 v0 = ((const f32x4*)xr)[tid * 2];
  f32x4 v1 = ((const f32x4*)xr)[tid * 2 + 1];
  float s = v0.x + v0.y + v0.z + v0.w + v1.x + v1.y + v1.z + v1.w;
  float ss = v0.x*v0.x + v0.y*v0.y + v0.z*v0.z + v0.w*v0.w
           + v1.x*v1.x + v1.y*v1.y + v1.z*v1.z + v1.w*v1.w;
  #pragma unroll
  for (int off = 32; off; off >>= 1) {
    s += __shfl_xor(s, off);
    ss += __shfl_xor(ss, off);
  }
  __shared__ float red[8];
  const int wv = tid >> 6, lane = tid & 63;
  if (lane == 0) { red[wv] = s; red[4 + wv] = ss; }
  __syncthreads();
  s = red[0] + red[1] + red[2] + red[3];
  ss = red[4] + red[5] + red[6] + red[7];
  const float mean = s * (1.0f / SD);
  const float var = ss * (1.0f / SD) - mean * mean;
  const float rstd = rsqrtf(var + 1e-5f);
  const int dbase = tid * 8;
  const float* wp = w + dbase; const float* bp = b + dbase;
  bf16x8 o;
  o[0] = (short)f2bf((v0.x - mean) * rstd * wp[0] + bp[0]);
  o[1] = (short)f2bf((v0.y - mean) * rstd * wp[1] + bp[1]);
  o[2] = (short)f2bf((v0.z - mean) * rstd * wp[2] + bp[2]);
  o[3] = (short)f2bf((v0.w - mean) * rstd * wp[3] + bp[3]);
  o[4] = (short)f2bf((v1.x - mean) * rstd * wp[4] + bp[4]);
  o[5] = (short)f2bf((v1.y - mean) * rstd * wp[5] + bp[5]);
  o[6] = (short)f2bf((v1.z - mean) * rstd * wp[6] + bp[6]);
  o[7] = (short)f2bf((v1.w - mean) * rstd * wp[7] + bp[7]);
  *(bf16x8*)(out + (size_t)row * SD + dbase) = o;
}

// ---------- bf16 NT GEMM: C[M,N] = A[M,K] @ B[N,K]^T + bias ----------
// EPI 0: bf16 out.  EPI 1: fp32 out = v + resid.  EPI 2: bf16 out = gelu(v).
// m97 structure: 128x128 tile, BK=32, 4 waves (2x2), 4x4 16x16x32 frags/wave,
// global_load_lds width-16 staging, 2 barriers per K-step.
template <int EPI>
__global__ __launch_bounds__(256) void gemm_nt(
    const u16* __restrict__ A, const u16* __restrict__ B,
    const float* __restrict__ bias, const float* __restrict__ resid,
    void* __restrict__ Cout, int M, int N, int K) {
  __shared__ u16 lA[128 * 32];
  __shared__ u16 lB[128 * 32];
  const int tid = threadIdx.x;
  const int w = tid >> 6, lane = tid & 63;
  const int nbn = N >> 7;
  int bid = blockIdx.x;
  if ((gridDim.x & 7) == 0) {  // bijective XCD swizzle
    const int per = gridDim.x >> 3;
    bid = (bid & 7) * per + (bid >> 3);
  }
  const int bm = bid / nbn, bn = bid % nbn;
  const int wr = w >> 1, wc = w & 1;
  const int fr = lane & 15;            // fragment row/col
  const int kg = (lane >> 4) << 3;     // k element offset within frag
  const int sr = lane >> 2;            // staging: row within 16-row chunk
  const int sk = (lane & 3) << 3;      // staging: k element offset
  f32x4 acc[4][4];
  #pragma unroll
  for (int i = 0; i < 4; ++i)
    #pragma unroll
    for (int j = 0; j < 4; ++j) acc[i][j] = (f32x4){0.f, 0.f, 0.f, 0.f};

  const size_t rowA0 = (size_t)bm * 128;
  const size_t rowB0 = (size_t)bn * 128;

  for (int kt = 0; kt < K; kt += 32) {
    #pragma unroll
    for (int c = 0; c < 2; ++c) {
      const int rt = ((w << 1) + c) * 16 + sr;
      async_copy16(A + (rowA0 + rt) * K + kt + sk, &lA[((w << 1) + c) * 512]);
      async_copy16(B + (rowB0 + rt) * K + kt + sk, &lB[((w << 1) + c) * 512]);
    }
    __syncthreads();  // drains vmcnt(0) before barrier
    bf16x8 af[4], bfr[4];
    #pragma unroll
    for (int mi = 0; mi < 4; ++mi)
      af[mi] = *(const bf16x8*)&lA[(wr * 64 + mi * 16 + fr) * 32 + kg];
    #pragma unroll
    for (int ni = 0; ni < 4; ++ni)
      bfr[ni] = *(const bf16x8*)&lB[(wc * 64 + ni * 16 + fr) * 32 + kg];
    #pragma unroll
    for (int mi = 0; mi < 4; ++mi)
      #pragma unroll
      for (int ni = 0; ni < 4; ++ni)
        acc[mi][ni] = MFMA16(af[mi], bfr[ni], acc[mi][ni]);
    __syncthreads();
  }

  const int rr = (lane >> 4) << 2;  // C/D: row = (lane>>4)*4 + i, col = lane&15
  #pragma unroll
  for (int mi = 0; mi < 4; ++mi) {
    #pragma unroll
    for (int i = 0; i < 4; ++i) {
      const int row = bm * 128 + wr * 64 + mi * 16 + rr + i;
      #pragma unroll
      for (int ni = 0; ni < 4; ++ni) {
        const int col = bn * 128 + wc * 64 + ni * 16 + fr;
        float v = acc[mi][ni][i] + bias[col];
        const size_t idx = (size_t)row * N + col;
        if (EPI == 0) {
          ((u16*)Cout)[idx] = f2bf(v);
        } else if (EPI == 1) {
          ((float*)Cout)[idx] = v + resid[idx];
        } else {
          float g = 0.5f * v * (1.0f + erff(v * 0.70710678118654752f));
          ((u16*)Cout)[idx] = f2bf(g);
        }
      }
    }
  }
}

// ---------- fused RMSNorm + RoPE (in place, bf16), one wave per 128-dim row ----------
__global__ __launch_bounds__(256) void rmsrope_kernel(u16* __restrict__ X,
                                                      const float* __restrict__ w,
                                                      const float* __restrict__ fc) {
  __shared__ float tmp[4][32];
  const int wv = threadIdx.x >> 6, lane = threadIdx.x & 63;
  const size_t row = (size_t)blockIdx.x * 4 + wv;   // 0 .. B*S*H-1, (b,s,h) order
  const int spos = (int)((row >> 4) & (SS - 1));    // row/H mod S
  u16* xp = X + row * SHD + lane * 2;
  float xa = bf2f(xp[0]), xb = bf2f(xp[1]);
  float ss = xa * xa + xb * xb;
  #pragma unroll
  for (int off = 32; off; off >>= 1) ss += __shfl_xor(ss, off);
  const float rs = rsqrtf(ss * (1.0f / SHD) + 1e-5f);
  const int d = lane * 2;
  float y0 = xa * rs * w[d];
  float y1 = xb * rs * w[d + 1];
  if (lane < 16) { tmp[wv][d] = y0; tmp[wv][d + 1] = y1; }
  __syncthreads();
  if (lane < 16) {
    const float a = tmp[wv][lane];
    const float bq = tmp[wv][lane + 16];
    const float c = fc[(spos * 16 + lane) * 2];
    const float sn = fc[(spos * 16 + lane) * 2 + 1];
    y0 = a * c - bq * sn;    // out dim 2*lane
    y1 = bq * c + a * sn;    // out dim 2*lane+1
  }
  xp[0] = f2bf(y0);
  xp[1] = f2bf(y1);
}

// ---------- causal flash attention ----------
// grid (S/64, B*H); 4 independent waves/block, 16 q-rows/wave, 32-key tiles.
__global__ __launch_bounds__(256) void attn_kernel(const u16* __restrict__ Q,
                                                   const u16* __restrict__ Kt,
                                                   const u16* __restrict__ V,
                                                   u16* __restrict__ Y) {
  __shared__ u16 Plds[4][512];  // per-wave 16x32 bf16 P bounce
  const int w = threadIdx.x >> 6, lane = threadIdx.x & 63;
  const int bh = blockIdx.y;
  const int b = bh >> 4, h = bh & 15;
  const int q0 = (blockIdx.x * 4 + w) * 16;
  const int fr = lane & 15, g = lane >> 4;
  const size_t base = ((size_t)b * SS) * SD + (size_t)h * SHD;  // rows stride SD

  bf16x8 qf[4];
  #pragma unroll
  for (int t = 0; t < 4; ++t)
    qf[t] = *(const bf16x8*)(Q + base + (size_t)(q0 + fr) * SD + t * 32 + g * 8);

  f32x4 O[8];
  #pragma unroll
  for (int dt = 0; dt < 8; ++dt) O[dt] = (f32x4){0.f, 0.f, 0.f, 0.f};
  f32x4 m = (f32x4){-3e38f, -3e38f, -3e38f, -3e38f};
  f32x4 l = (f32x4){0.f, 0.f, 0.f, 0.f};
  const int qrow = q0 + g * 4;

  const int ktiles = (q0 + 47) >> 5;  // cover keys <= q0+15
  for (int kt = 0; kt < ktiles; ++kt) {
    const int k0 = kt * 32;
    f32x4 s[2];
    #pragma unroll
    for (int sub = 0; sub < 2; ++sub) {
      s[sub] = (f32x4){0.f, 0.f, 0.f, 0.f};
      const u16* Kp = Kt + base + (size_t)(k0 + sub * 16 + fr) * SD + g * 8;
      #pragma unroll
      for (int t = 0; t < 4; ++t) {
        bf16x8 kf = *(const bf16x8*)(Kp + t * 32);
        s[sub] = MFMA16(qf[t], kf, s[sub]);
      }
      const int key = k0 + sub * 16 + fr;
      #pragma unroll
      for (int i = 0; i < 4; ++i) {
        float val = s[sub][i] * ATT_SCALE;
        if (key > qrow + i) val = NEGINF_MASK;
        s[sub][i] = val;
      }
    }
    // online softmax over the 16-lane groups (key axis)
    f32x4 mx;
    #pragma unroll
    for (int i = 0; i < 4; ++i) mx[i] = fmaxf(s[0][i], s[1][i]);
    #pragma unroll
    for (int off = 1; off < 16; off <<= 1)
      #pragma unroll
      for (int i = 0; i < 4; ++i) mx[i] = fmaxf(mx[i], __shfl_xor(mx[i], off));
    f32x4 mnew, alpha, rsum;
    #pragma unroll
    for (int i = 0; i < 4; ++i) {
      mnew[i] = fmaxf(m[i], mx[i]);
      alpha[i] = __expf(m[i] - mnew[i]);
      rsum[i] = 0.f;
    }
    #pragma unroll
    for (int sub = 0; sub < 2; ++sub)
      #pragma unroll
      for (int i = 0; i < 4; ++i) {
        float p = __expf(s[sub][i] - mnew[i]);
        s[sub][i] = p;
        rsum[i] += p;
      }
    #pragma unroll
    for (int off = 1; off < 16; off <<= 1)
      #pragma unroll
      for (int i = 0; i < 4; ++i) rsum[i] += __shfl_xor(rsum[i], off);
    #pragma unroll
    for (int i = 0; i < 4; ++i) {
      l[i] = l[i] * alpha[i] + rsum[i];
      m[i] = mnew[i];
    }
    #pragma unroll
    for (int dt = 0; dt < 8; ++dt)
      #pragma unroll
      for (int i = 0; i < 4; ++i) O[dt][i] *= alpha[i];
    // P (D-layout) -> LDS -> A-layout frag
    u16* Pl = Plds[w];
    #pragma unroll
    for (int sub = 0; sub < 2; ++sub)
      #pragma unroll
      for (int i = 0; i < 4; ++i)
        Pl[(g * 4 + i) * 32 + sub * 16 + fr] = f2bf(s[sub][i]);
    asm volatile("s_waitcnt lgkmcnt(0)" ::: "memory");
    bf16x8 pf = *(const bf16x8*)&Pl[fr * 32 + g * 8];
    // PV: B-frag of V gathered from global (L2/L3-resident at this size)
    #pragma unroll
    for (int dt = 0; dt < 8; ++dt) {
      const u16* Vp = V + base + (size_t)(k0 + g * 8) * SD + dt * 16 + fr;
      bf16x8 vf;
      #pragma unroll
      for (int i = 0; i < 8; ++i) vf[i] = (short)Vp[(size_t)i * SD];
      O[dt] = MFMA16(pf, vf, O[dt]);
    }
  }
  // epilogue: O / l -> Y (bf16)
  f32x4 li;
  #pragma unroll
  for (int i = 0; i < 4; ++i) li[i] = 1.0f / l[i];
  #pragma unroll
  for (int dt = 0; dt < 8; ++dt)
    #pragma unroll
    for (int i = 0; i < 4; ++i)
      Y[base + (size_t)(qrow + i) * SD + dt * 16 + fr] = f2bf(O[dt][i] * li[i]);
}

// ---------- host ----------
extern "C" void kernel_launch(void* const* d_in, const int* in_sizes, int n_in,
                              void* d_out, int out_size, void* d_ws, size_t ws_size,
                              hipStream_t stream) {
  const float* x0 = (const float*)d_in[0];
  const float* x1 = (const float*)d_in[1];
  const float* x2 = (const float*)d_in[2];
  const float* x3 = (const float*)d_in[3];
  const float* fc = (const float*)d_in[5];
  const float* wq_w = (const float*)d_in[7];
  const float* wq_b = (const float*)d_in[8];
  const float* wk_w = (const float*)d_in[9];
  const float* wk_b = (const float*)d_in[10];
  const float* wv_w = (const float*)d_in[11];
  const float* wv_b = (const float*)d_in[12];
  const float* wo_w = (const float*)d_in[13];
  const float* wo_b = (const float*)d_in[14];
  const float* qn_w = (const float*)d_in[15];
  const float* kn_w = (const float*)d_in[16];
  const float* ln0_w = (const float*)d_in[17];
  const float* ln0_b = (const float*)d_in[18];
  const float* ln1_w = (const float*)d_in[19];
  const float* ln1_b = (const float*)d_in[20];
  const float* ln2_w = (const float*)d_in[21];
  const float* ln2_b = (const float*)d_in[22];
  const float* fln_w = (const float*)d_in[23];
  const float* fln_b = (const float*)d_in[24];
  const float* w1_w = (const float*)d_in[25];
  const float* w1_b = (const float*)d_in[26];
  const float* w2_w = (const float*)d_in[27];
  const float* w2_b = (const float*)d_in[28];

  char* ws = (char*)d_ws;
  size_t off = 0;
  auto alloc = [&](size_t bytes) {
    void* p = ws + off;
    off += (bytes + 255) & ~(size_t)255;
    return p;
  };
  const size_t ROWS = (size_t)SB * SS;  // 4096
  u16* LN4 = (u16*)alloc(4 * ROWS * SD * 2);          // nq|nk|nv|fx
  u16* Qb = (u16*)alloc(ROWS * SD * 2);
  u16* Kb = (u16*)alloc(ROWS * SD * 2);
  u16* Vb = (u16*)alloc(ROWS * SD * 2);
  u16* MID = (u16*)alloc(ROWS * SHID * 2);
  u16* Wq = (u16*)alloc((size_t)SD * SD * 2);
  u16* Wk = (u16*)alloc((size_t)SD * SD * 2);
  u16* Wv = (u16*)alloc((size_t)SD * SD * 2);
  u16* Wo = (u16*)alloc((size_t)SD * SD * 2);
  u16* W1 = (u16*)alloc((size_t)SHID * SD * 2);
  u16* W2 = (u16*)alloc((size_t)SHID * SD * 2);

  u16* NQ = LN4;
  u16* NK = LN4 + ROWS * SD;
  u16* NV = LN4 + 2 * ROWS * SD;
  u16* FX = LN4 + 3 * ROWS * SD;
  u16* Yb = NQ;             // alias: NQ dead after Q projection
  float* Hb = (float*)NK;   // alias: NK+NV (32 MB) dead after K/V projections

  // 1) weights -> bf16 (single fused dispatch)
  const int n4_d2 = SD * SD / 4;        // 1048576
  const int n4_hid = SHID * SD / 4;     // 3014656
  CvtArgs ca;
  ca.src[0] = wq_w; ca.dst[0] = Wq;
  ca.src[1] = wk_w; ca.dst[1] = Wk;
  ca.src[2] = wv_w; ca.dst[2] = Wv;
  ca.src[3] = wo_w; ca.dst[3] = Wo;
  ca.src[4] = w1_w; ca.dst[4] = W1;
  ca.src[5] = w2_w; ca.dst[5] = W2;
  int acc4 = 0;
  const int segn[6] = {n4_d2, n4_d2, n4_d2, n4_d2, n4_hid, n4_hid};
  for (int s = 0; s < 6; ++s) { acc4 += segn[s]; ca.end4[s] = acc4; }
  cvt6_kernel<<<2048, 256, 0, stream>>>(ca, acc4);

  // 2) layernorms
  ln4_kernel<<<4 * (int)ROWS, 256, 0, stream>>>(x0, x1, x2, x3, ln0_w, ln0_b,
                                                ln1_w, ln1_b, ln2_w, ln2_b,
                                                fln_w, fln_b, LN4);

  // 3) QKV projections (bf16 out)
  gemm_nt<0><<<512, 256, 0, stream>>>(NQ, Wq, wq_b, nullptr, Qb, (int)ROWS, SD, SD);
  gemm_nt<0><<<512, 256, 0, stream>>>(NK, Wk, wk_b, nullptr, Kb, (int)ROWS, SD, SD);
  gemm_nt<0><<<512, 256, 0, stream>>>(NV, Wv, wv_b, nullptr, Vb, (int)ROWS, SD, SD);

  // 4) rmsnorm + rope on q,k
  rmsrope_kernel<<<16384, 256, 0, stream>>>(Qb, qn_w, fc);
  rmsrope_kernel<<<16384, 256, 0, stream>>>(Kb, kn_w, fc);

  // 5) flash attention -> Yb
  attn_kernel<<<dim3(SS / 64, SB * SH), 256, 0, stream>>>(Qb, Kb, Vb, Yb);

  // 6) FFN up + gelu (uses FX; Hb alias does not overlap FX)
  gemm_nt<2><<<1472, 256, 0, stream>>>(FX, W1, w1_b, nullptr, MID, (int)ROWS, SHID, SD);

  // 7) attn out projection + x3 residual -> h (fp32)
  gemm_nt<1><<<512, 256, 0, stream>>>(Yb, Wo, wo_b, x3, Hb, (int)ROWS, SD, SD);

  // 8) FFN down + h residual -> out (fp32)
  gemm_nt<1><<<512, 256, 0, stream>>>(MID, W2, w2_b, Hb, (float*)d_out, (int)ROWS, SD, SHID);
}